// Round 7
// baseline (283.495 us; speedup 1.0000x reference)
//
#include <hip/hip_runtime.h>

// CustomRNN: B=2048, T=512, I=1, H=64. One wave per batch.
// Evolution:
//  R0: full-h LDS broadcast (16 ds_read_b128/step), 172us (LDS-BW-bound).
//  R2: 4-way K-split + shfl_xor butterfly, 158us (2 serial bpermute hops).
//  R4: readlane broadcast, 228us (issue explosion). Reverted.
//  R5: quad-local DPP butterfly + LDS h round-trip, 134us.
//  R6: f16 dot2 — NO change (138us): dot2 = 2 MAC/instr = pk_fma_f32;
//      instruction count unchanged. Diagnostic: wall 647cy/step/SIMD,
//      VALU issue 498cy (77%) -> LATENCY-bound, L ~= 650cy, n=2 chains/SIMD
//      is fixed by B. Only lever: shrink L. Biggest L term: the LDS h
//      round-trip (ds_write -> visibility -> barrier -> ds_read).
//  R7 (this): h never touches LDS. Lane l keeps h[l] in hcur.
//   - k-segment = own row: lane l (g=l>>4) covers cols [16g,16g+16), so
//     the h it needs = its own row's 16 hcur values -> allgather via 16
//     INDEPENDENT __shfl(hcur, 16g+j) = 16 back-to-back ds_bpermute =
//     ONE pipelined LDS-latency hop (replaces write+barrier+read = 2 hops
//     + waitcnt drain).
//   - acc[k] accumulates row (l&15)+16*((g+k)&3): the rotation makes the
//     combine select-free AND register-uniform:
//       a(l) = acc0 + shfl(acc3,l+16) + shfl(acc2,l+32) + shfl(acc1,l+48)
//     (3 independent bpermutes = one more hop). Verified lane 37: row 37
//     covered over cols {32-47,48-63,0-15,16-31} exactly once.
//   - all transport is plain __shfl with explicit source lanes (semantics
//     harness-proven in R2); no DPP-direction or permlane guesses; f32
//     everywhere (absmax 0).
// Expected L: allgather(~130) + dots(~35) + combine(~130) + tanh(~50)
//   ~= 370cy vs 650 -> ~80-100us.

typedef float v2f __attribute__((ext_vector_type(2)));
typedef float v4f __attribute__((ext_vector_type(4)));

#define WPB 4  // waves (== batches) per block

__global__ __launch_bounds__(WPB * 64)
__attribute__((amdgpu_waves_per_eu(2, 2)))  // pin VGPR budget: weight cache
void rnn_fused(
    const float* __restrict__ x,      // [B, T, 1]
    const float* __restrict__ W_ih,   // [64, 1]
    const float* __restrict__ W_hh,   // [64, 64]
    const float* __restrict__ b_ih,   // [64]
    const float* __restrict__ b_hh,   // [64]
    const float* __restrict__ fc_w,   // [1, 64]
    const float* __restrict__ fc_b,   // [1]
    float* __restrict__ out,          // [B, 1]
    int B, int T)
{
    const int lane  = threadIdx.x & 63;
    const int wv    = threadIdx.x >> 6;
    const int batch = blockIdx.x * WPB + wv;
    if (batch >= B) return;  // whole-wave exit; no block-wide sync anywhere

    const int g    = lane >> 4;      // row-group; k-cols [16g, 16g+16)
    const int c15  = lane & 15;
    const int col0 = g << 4;
    const int rowbase = g << 4;      // first lane of this row == first col

    __shared__ __align__(16) float xs[WPB][64];

    // acc[k] accumulates row rk = c15 + 16*((g+k)&3) over cols [col0,col0+16).
    // k=0 -> own row (rk == lane).
    int rk[4];
#pragma unroll
    for (int k = 0; k < 4; ++k) rk[k] = c15 + 16 * ((g + k) & 3);

    // 4 rows x 16 cols of W_hh per lane = 64 f32 = 64 VGPRs (as v2f).
    v2f w0[8], w1[8], w2[8], w3[8];
    {
        const v2f* p0 = (const v2f*)(W_hh + rk[0] * 64 + col0);
        const v2f* p1 = (const v2f*)(W_hh + rk[1] * 64 + col0);
        const v2f* p2 = (const v2f*)(W_hh + rk[2] * 64 + col0);
        const v2f* p3 = (const v2f*)(W_hh + rk[3] * 64 + col0);
#pragma unroll
        for (int i = 0; i < 8; ++i) {
            w0[i] = p0[i];
            w1[i] = p1[i];
            w2[i] = p2[i];
            w3[i] = p3[i];
        }
    }
    const float wih_j  = W_ih[lane];           // a lands as row `lane`
    const float bias_j = b_ih[lane] + b_hh[lane];

    // Combine source lanes (loop-invariant; hoisted bpermute addresses).
    const int cj1 = (lane + 16) & 63;
    const int cj2 = (lane + 32) & 63;
    const int cj3 = (lane + 48) & 63;

    const float* xb = x + (size_t)batch * T;

    float hcur = 0.0f;  // lane l holds h[l]; the ONLY copy of h

    auto step = [&](float xv) {
        // Allgather own row's h: 16 independent bpermutes, one latency hop.
        float hr[16];
#pragma unroll
        for (int j = 0; j < 16; ++j)
            hr[j] = __shfl(hcur, rowbase + j, 64);

        v2f a0 = {0.f, 0.f}, a1 = {0.f, 0.f}, a2 = {0.f, 0.f}, a3 = {0.f, 0.f};
#pragma unroll
        for (int i = 0; i < 8; ++i) {
            const v2f hp = {hr[2 * i], hr[2 * i + 1]};
            a0 = __builtin_elementwise_fma(hp, w0[i], a0);
            a1 = __builtin_elementwise_fma(hp, w1[i], a1);
            a2 = __builtin_elementwise_fma(hp, w2[i], a2);
            a3 = __builtin_elementwise_fma(hp, w3[i], a3);
        }
        const float s0 = a0.x + a0.y, s1 = a1.x + a1.y;
        const float s2 = a2.x + a2.y, s3 = a3.x + a3.y;

        // Select-free, register-uniform combine (3 independent bpermutes):
        // a(l) = row-l dot over all 64 cols.
        const float z = s0 + __shfl(s3, cj1, 64)
                           + __shfl(s2, cj2, 64)
                           + __shfl(s1, cj3, 64);
        const float a = z + __builtin_fmaf(xv, wih_j, bias_j);

        // tanh(a) = sign(a) * (1 - e) / (1 + e),  e = exp(-2|a|)
        const float ax = __builtin_fabsf(a);
        const float e  = __builtin_amdgcn_exp2f(ax * -2.885390082f); // exp(-2ax)
        const float rc = __builtin_amdgcn_rcpf(1.0f + e);
        hcur = __builtin_copysignf((1.0f - e) * rc, a);
        // No write-back: next step's allgather reads hcur directly.
    };

    for (int t0 = 0; t0 < T; t0 += 64) {
        const int rem = T - t0;
        // Stage up to 64 input scalars for this batch (coalesced 256B load).
        xs[wv][lane] = (lane < rem) ? xb[t0 + lane] : 0.0f;
        __builtin_amdgcn_wave_barrier();

        if (rem >= 64) {
            const v4f* xs4 = (const v4f*)(&xs[wv][0]);
            for (int t4 = 0; t4 < 16; ++t4) {
                const v4f xq = xs4[t4];  // one broadcast b128 per 4 steps
                step(xq.x);
                step(xq.y);
                step(xq.z);
                step(xq.w);
            }
        } else {
            for (int tt = 0; tt < rem; ++tt) step(xs[wv][tt]);
        }
        __builtin_amdgcn_wave_barrier();  // xs reads done before restaging
    }

    // fc: out[b] = sum_j h[j] * fc_w[j] + fc_b   (lane j holds h[j])
    float v = hcur * fc_w[lane];
#pragma unroll
    for (int off = 32; off > 0; off >>= 1)
        v += __shfl_xor(v, off, 64);
    if (lane == 0) out[batch] = v + fc_b[0];
}

extern "C" void kernel_launch(void* const* d_in, const int* in_sizes, int n_in,
                              void* d_out, int out_size, void* d_ws, size_t ws_size,
                              hipStream_t stream) {
    const float* x    = (const float*)d_in[0];
    const float* W_ih = (const float*)d_in[1];
    const float* W_hh = (const float*)d_in[2];
    const float* b_ih = (const float*)d_in[3];
    const float* b_hh = (const float*)d_in[4];
    const float* fc_w = (const float*)d_in[5];
    const float* fc_b = (const float*)d_in[6];
    float* out = (float*)d_out;

    const int B = out_size;          // output is [B, 1]
    const int T = in_sizes[0] / B;   // I == 1, so x has B*T elements

    const int blocks = (B + WPB - 1) / WPB;
    rnn_fused<<<blocks, WPB * 64, 0, stream>>>(x, W_ih, W_hh, b_ih, b_hh,
                                               fc_w, fc_b, out, B, T);
}

// Round 9
// 214.457 us; speedup vs baseline: 1.3219x; 1.3219x over previous
//
#include <hip/hip_runtime.h>

// CustomRNN: B=2048, T=512, I=1, H=64. One wave per batch.
// Evolution:
//  R0: full-h LDS broadcast, 172us (LDS-BW).      R2: K-split+shfl, 158us.
//  R4: readlane, 228us (issue). R5: quad-DPP butterfly + LDS h, 134us --
//      wall == L_chain (628cy): issue 440 fits under; ONLY the per-step
//      critical path matters (B gives exactly 2 chains/SIMD).
//  R6: f16 dot2 swap, no change (dot2 issue == pk_fma; unpack washed it).
//      But validated f16-W/f16-h numerics: absmax 2e-3 << 7.9e-3.
//  R7: register-h + 16-shfl allgather + 3-shfl combine: mapping CORRECT
//      (absmax 0.0) but w[64]f32+hr[16]+addrs > 88 VGPR -> scratch spills
//      -> 252us (VALUBusy 37% = scratch-latency signature).
//  R8: same structure at half register cost — failed to COMPILE only:
//      cvt_pkrtz returns __fp16-vector, needs bit_cast to _Float16-vector.
//  R9 (this): R8 with the bit_cast fix. Structure:
//   - W as f16x2: 32 VGPRs. h transported PACKED: after tanh, lane packs
//     (h[even],h[odd]) of its pair via DPP xor1 + parity-ordered cvt_pk;
//     allgather of own 16-col segment = 8 __shfl of u32 = ONE pipelined
//     LDS-pipe hop. Dot = 32 v_dot2_f32_f16, f32 accumulators, no
//     horizontal adds. Combine = R7's proven 3-shfl rotation (hop 2).
//   - No barriers, no ds_write, no h in LDS. ~75 live VGPRs < 88.
//  Mapping (g=lane>>4, c15=lane&15; cols [16g,16g+16)):
//   acc_k covers row c15+16*((g+k)&3); a(l) = acc0 + shfl(acc3,l+16)
//   + shfl(acc2,l+32) + shfl(acc1,l+48)  [R7: absmax 0.0].
// Chain: pack(12) + hop(130) + dot2 chain(35) + hop(130) + adds/bias(16)
//   + tanh(45) ~= 370-430cy vs R5's 628 -> predict ~85-105us rocprof.

typedef float v2f __attribute__((ext_vector_type(2)));
typedef float v4f __attribute__((ext_vector_type(4)));
typedef _Float16 f16;
typedef _Float16 f16x2 __attribute__((ext_vector_type(2)));

#define WPB 4  // waves (== batches) per block

#define DPP_XOR1 0xB1  // quad_perm:[1,0,3,2]

#if __has_builtin(__builtin_amdgcn_mov_dpp)
template <int CTRL>
__device__ __forceinline__ float qperm(float x) {
    return __int_as_float(__builtin_amdgcn_mov_dpp(
        __float_as_int(x), CTRL, 0xF, 0xF, true));
}
#else
template <int CTRL>
__device__ __forceinline__ float qperm(float x) {
    return __shfl_xor(x, 1, 64);  // CTRL==DPP_XOR1 only
}
#endif

__device__ __forceinline__ float fdot2(f16x2 a, f16x2 b, float c) {
#if __has_builtin(__builtin_amdgcn_fdot2)
    return __builtin_amdgcn_fdot2(a, b, c, false);
#else
    return __builtin_fmaf((float)a.x, (float)b.x,
           __builtin_fmaf((float)a.y, (float)b.y, c));
#endif
}

__device__ __forceinline__ f16x2 pack_pair(float lo, float hi) {
#if __has_builtin(__builtin_amdgcn_cvt_pkrtz)
    // cvt_pkrtz returns __fp16 ext_vector(2); bit-identical to f16x2.
    return __builtin_bit_cast(f16x2, __builtin_amdgcn_cvt_pkrtz(lo, hi));
#else
    return (f16x2){(f16)lo, (f16)hi};
#endif
}

__global__ __launch_bounds__(WPB * 64)
__attribute__((amdgpu_waves_per_eu(2, 2)))  // pin VGPR budget: weight cache
void rnn_fused(
    const float* __restrict__ x,      // [B, T, 1]
    const float* __restrict__ W_ih,   // [64, 1]
    const float* __restrict__ W_hh,   // [64, 64]
    const float* __restrict__ b_ih,   // [64]
    const float* __restrict__ b_hh,   // [64]
    const float* __restrict__ fc_w,   // [1, 64]
    const float* __restrict__ fc_b,   // [1]
    float* __restrict__ out,          // [B, 1]
    int B, int T)
{
    const int lane  = threadIdx.x & 63;
    const int wv    = threadIdx.x >> 6;
    const int batch = blockIdx.x * WPB + wv;
    if (batch >= B) return;  // whole-wave exit; no block-wide sync anywhere

    const int g    = lane >> 4;      // col segment: [16g, 16g+16)
    const int c15  = lane & 15;
    const int col0 = g << 4;

    __shared__ __align__(16) float xs[WPB][64];

    // acc_k accumulates row rk = c15 + 16*((g+k)&3) over cols [col0,col0+16).
    int rk[4];
#pragma unroll
    for (int k = 0; k < 4; ++k) rk[k] = c15 + 16 * ((g + k) & 3);

    // 4 rows x 16 cols of W_hh per lane, packed f16: 4 x 8 f16x2 = 32 VGPRs.
    f16x2 w0[8], w1[8], w2[8], w3[8];
    {
        const v2f* p0 = (const v2f*)(W_hh + rk[0] * 64 + col0);
        const v2f* p1 = (const v2f*)(W_hh + rk[1] * 64 + col0);
        const v2f* p2 = (const v2f*)(W_hh + rk[2] * 64 + col0);
        const v2f* p3 = (const v2f*)(W_hh + rk[3] * 64 + col0);
#pragma unroll
        for (int i = 0; i < 8; ++i) {
            const v2f t0 = p0[i], t1 = p1[i], t2 = p2[i], t3 = p3[i];
            w0[i] = pack_pair(t0.x, t0.y);
            w1[i] = pack_pair(t1.x, t1.y);
            w2[i] = pack_pair(t2.x, t2.y);
            w3[i] = pack_pair(t3.x, t3.y);
        }
    }
    const float wih_j  = W_ih[lane];           // a lands as row `lane`
    const float bias_j = b_ih[lane] + b_hh[lane];

    // Allgather sources: pair j of own segment lives on lane 16g + 2j
    // (both lanes of a pair hold the packed value; take the even one).
    int src[8];
#pragma unroll
    for (int j = 0; j < 8; ++j) src[j] = (lane & 0x30) | (2 * j);
    // Combine sources (R7-proven rotation).
    const int cj1 = (lane + 16) & 63;
    const int cj2 = (lane + 32) & 63;
    const int cj3 = (lane + 48) & 63;

    const float* xb = x + (size_t)batch * T;

    float hcur = 0.0f;  // lane l holds h[l]; the ONLY copy of h
    const int odd = lane & 1;

    auto step = [&](float xv) {
        // Pack pair (h[2m], h[2m+1]) into one f16x2 on BOTH lanes of the
        // pair: neighbor via DPP xor1 (VALU), parity-ordered operands.
        const float nbr = qperm<DPP_XOR1>(hcur);
        const float plo = odd ? nbr : hcur;
        const float phi = odd ? hcur : nbr;
        const int pkBits = __builtin_bit_cast(int, pack_pair(plo, phi));

        // Allgather own segment: 8 independent shfl = one pipelined hop.
        int hb[8];
#pragma unroll
        for (int j = 0; j < 8; ++j) hb[j] = __shfl(pkBits, src[j], 64);

        // 4 rows x 8 dot2 (2 f16 MAC each), f32 accumulate, no h-adds.
        float a0 = 0.f, a1 = 0.f, a2 = 0.f, a3 = 0.f;
#pragma unroll
        for (int j = 0; j < 8; ++j) {
            const f16x2 hp = __builtin_bit_cast(f16x2, hb[j]);
            a0 = fdot2(hp, w0[j], a0);
            a1 = fdot2(hp, w1[j], a1);
            a2 = fdot2(hp, w2[j], a2);
            a3 = fdot2(hp, w3[j], a3);
        }

        // Combine: 3 independent shfl = one hop (mapping R7: absmax 0.0).
        const float z = a0 + __shfl(a3, cj1, 64)
                           + __shfl(a2, cj2, 64)
                           + __shfl(a1, cj3, 64);
        const float a = z + __builtin_fmaf(xv, wih_j, bias_j);

        // tanh(a) = sign(a) * (1 - e) / (1 + e),  e = exp(-2|a|)
        const float ax = __builtin_fabsf(a);
        const float e  = __builtin_amdgcn_exp2f(ax * -2.885390082f); // exp(-2ax)
        const float rc = __builtin_amdgcn_rcpf(1.0f + e);
        hcur = __builtin_copysignf((1.0f - e) * rc, a);
    };

    for (int t0 = 0; t0 < T; t0 += 64) {
        const int rem = T - t0;
        // Stage up to 64 input scalars for this batch (coalesced 256B load).
        xs[wv][lane] = (lane < rem) ? xb[t0 + lane] : 0.0f;
        __builtin_amdgcn_wave_barrier();

        if (rem >= 64) {
            const v4f* xs4 = (const v4f*)(&xs[wv][0]);
            for (int t4 = 0; t4 < 16; ++t4) {
                const v4f xq = xs4[t4];  // one broadcast b128 per 4 steps
                step(xq.x);
                step(xq.y);
                step(xq.z);
                step(xq.w);
            }
        } else {
            for (int tt = 0; tt < rem; ++tt) step(xs[wv][tt]);
        }
        __builtin_amdgcn_wave_barrier();  // xs reads done before restaging
    }

    // fc: out[b] = sum_j h[j] * fc_w[j] + fc_b   (lane j holds h[j], f32)
    float v = hcur * fc_w[lane];
#pragma unroll
    for (int off = 32; off > 0; off >>= 1)
        v += __shfl_xor(v, off, 64);
    if (lane == 0) out[batch] = v + fc_b[0];
}

extern "C" void kernel_launch(void* const* d_in, const int* in_sizes, int n_in,
                              void* d_out, int out_size, void* d_ws, size_t ws_size,
                              hipStream_t stream) {
    const float* x    = (const float*)d_in[0];
    const float* W_ih = (const float*)d_in[1];
    const float* W_hh = (const float*)d_in[2];
    const float* b_ih = (const float*)d_in[3];
    const float* b_hh = (const float*)d_in[4];
    const float* fc_w = (const float*)d_in[5];
    const float* fc_b = (const float*)d_in[6];
    float* out = (float*)d_out;

    const int B = out_size;          // output is [B, 1]
    const int T = in_sizes[0] / B;   // I == 1, so x has B*T elements

    const int blocks = (B + WPB - 1) / WPB;
    rnn_fused<<<blocks, WPB * 64, 0, stream>>>(x, W_ih, W_hh, b_ih, b_hh,
                                               fc_w, fc_b, out, B, T);
}